// Round 1
// baseline (961.529 us; speedup 1.0000x reference)
//
#include <hip/hip_runtime.h>
#include <stdint.h>
#include <stddef.h>

// Problem constants
#define N_Q 256        // queries
#define M_D 50000      // dataset rows
#define K_D 3072       // feature dim
#define MTILE 64       // dataset rows per workgroup in scores GEMM
#define BK 32          // K-slice per iteration
#define CAND_CAP 128   // max candidates per row
#define WINDOW 9.0f    // raw-score candidate window (36 logits; bf16 err bound ~0.6)

typedef short bf16x8 __attribute__((ext_vector_type(8)));   // 8 bf16 = 4 VGPRs
typedef float f32x4 __attribute__((ext_vector_type(4)));

// fp32 -> bf16 round-to-nearest-even
static __device__ inline unsigned short f2bf(float f) {
    unsigned int u = __float_as_uint(f);
    u += 0x7fffu + ((u >> 16) & 1u);
    return (unsigned short)(u >> 16);
}

// ---------------------------------------------------------------------------
// K0: convert x [256x3072] fp32 -> bf16
// ---------------------------------------------------------------------------
__global__ __launch_bounds__(256) void cvt_x_kernel(const float* __restrict__ x,
                                                    short* __restrict__ xb) {
    int i = (blockIdx.x * 256 + threadIdx.x) * 4;   // grid covers exactly 786432
    float4 f = *(const float4*)(x + i);
    ushort4 o;
    o.x = f2bf(f.x); o.y = f2bf(f.y); o.z = f2bf(f.z); o.w = f2bf(f.w);
    *(ushort4*)(xb + i) = o;
}

// ---------------------------------------------------------------------------
// K1: scores[n][m] = sum_k xb[n][k] * bf16(dataset[m][k])   (raw dot, no temp)
// One WG computes a 256x64 tile of scores (all N, MTILE dataset rows).
// 4 waves, wave w handles output rows [w*64, w*64+64), all 64 cols.
// ---------------------------------------------------------------------------
__global__ __launch_bounds__(256) void gemm_scores(const short* __restrict__ xb,
                                                   const float* __restrict__ dset,
                                                   float* __restrict__ scores) {
    __shared__ __align__(16) short sA[N_Q * BK];    // 256x32 bf16 = 16 KB
    __shared__ __align__(16) short sB[MTILE * BK];  // 64x32 bf16 = 4 KB

    const int tid = threadIdx.x;
    const int w = tid >> 6;        // wave 0..3
    const int l = tid & 63;        // lane
    const int m0 = blockIdx.x * MTILE;

    f32x4 acc[4][4];
#pragma unroll
    for (int i = 0; i < 4; ++i)
#pragma unroll
        for (int j = 0; j < 4; ++j)
            acc[i][j] = (f32x4){0.f, 0.f, 0.f, 0.f};

    // B staging map: 4 threads per dataset row, 8 floats each
    const int br = tid >> 2;                 // 0..63 local row
    const int bq = tid & 3;                  // quarter of the 32-float slice
    const bool bvalid = (m0 + br) < M_D;
    const float* bsrc = dset + (size_t)(m0 + br) * K_D + bq * 8;

    const int kk = (l >> 4) * 8;             // lane's k-offset within frag
    const int rA = l & 15;                   // lane's row-within-16 for A/B frags

    for (int kt = 0; kt < K_D / BK; ++kt) {
        __syncthreads();   // previous iteration's ds_reads complete

        // --- stage A: 256 rows x 32 bf16 from xb, fully coalesced 16B chunks
#pragma unroll
        for (int j = 0; j < 4; ++j) {
            int c = j * 256 + tid;           // 16B chunk id, 4 chunks per row
            int row = c >> 2;
            int off = c & 3;
            bf16x8 v = *(const bf16x8*)(xb + (size_t)row * K_D + kt * BK + off * 8);
            *(bf16x8*)&sA[c * 8] = v;
        }
        // --- stage B: 64 rows x 32 fp32 -> bf16 (masked at M edge)
        {
            bf16x8 pk;
            if (bvalid) {
                const float* p = bsrc + kt * BK;
                float4 f0 = *(const float4*)p;
                float4 f1 = *(const float4*)(p + 4);
                pk[0] = (short)f2bf(f0.x); pk[1] = (short)f2bf(f0.y);
                pk[2] = (short)f2bf(f0.z); pk[3] = (short)f2bf(f0.w);
                pk[4] = (short)f2bf(f1.x); pk[5] = (short)f2bf(f1.y);
                pk[6] = (short)f2bf(f1.z); pk[7] = (short)f2bf(f1.w);
            } else {
                pk = (bf16x8){0, 0, 0, 0, 0, 0, 0, 0};
            }
            *(bf16x8*)&sB[br * BK + bq * 8] = pk;
        }
        __syncthreads();

        // --- fragments + MFMA
        bf16x8 af[4], bfr[4];
#pragma unroll
        for (int ai = 0; ai < 4; ++ai)
            af[ai] = *(const bf16x8*)&sA[(w * 64 + ai * 16 + rA) * BK + kk];
#pragma unroll
        for (int bj = 0; bj < 4; ++bj)
            bfr[bj] = *(const bf16x8*)&sB[(bj * 16 + rA) * BK + kk];
#pragma unroll
        for (int ai = 0; ai < 4; ++ai)
#pragma unroll
            for (int bj = 0; bj < 4; ++bj)
                acc[ai][bj] = __builtin_amdgcn_mfma_f32_16x16x32_bf16(
                    af[ai], bfr[bj], acc[ai][bj], 0, 0, 0);
    }

    // epilogue: C/D layout col = l&15, row = (l>>4)*4 + r  [m89-verified]
    const int crow = (l >> 4) * 4;
    const int ccol = l & 15;
#pragma unroll
    for (int ai = 0; ai < 4; ++ai) {
#pragma unroll
        for (int bj = 0; bj < 4; ++bj) {
            int m = m0 + bj * 16 + ccol;
            if (m < M_D) {
#pragma unroll
                for (int r = 0; r < 4; ++r) {
                    int n = w * 64 + ai * 16 + crow + r;
                    scores[(size_t)n * M_D + m] = acc[ai][bj][r];
                }
            }
        }
    }
}

// ---------------------------------------------------------------------------
// K2: per row: max over M, then collect candidates with s >= max - WINDOW
// ---------------------------------------------------------------------------
__global__ __launch_bounds__(256) void scan_rows(const float* __restrict__ scores,
                                                 int* __restrict__ cidx,
                                                 int* __restrict__ ccnt) {
    const int n = blockIdx.x;
    const int tid = threadIdx.x;
    const float4* row4 = (const float4*)(scores + (size_t)n * M_D);  // 12500 vec4

    float mx = -3.0e38f;
    for (int m4 = tid; m4 < M_D / 4; m4 += 256) {
        float4 v = row4[m4];
        mx = fmaxf(mx, fmaxf(fmaxf(v.x, v.y), fmaxf(v.z, v.w)));
    }
#pragma unroll
    for (int off = 32; off > 0; off >>= 1) mx = fmaxf(mx, __shfl_down(mx, off));

    __shared__ float wred[4];
    __shared__ int cnt;
    if ((tid & 63) == 0) wred[tid >> 6] = mx;
    if (tid == 0) cnt = 0;
    __syncthreads();
    float rowmax = fmaxf(fmaxf(wred[0], wred[1]), fmaxf(wred[2], wred[3]));
    float thr = rowmax - WINDOW;

    for (int m4 = tid; m4 < M_D / 4; m4 += 256) {
        float4 v = row4[m4];
        if (v.x >= thr || v.y >= thr || v.z >= thr || v.w >= thr) {
            float e[4] = {v.x, v.y, v.z, v.w};
#pragma unroll
            for (int j = 0; j < 4; ++j) {
                if (e[j] >= thr) {
                    int p = atomicAdd(&cnt, 1);
                    if (p < CAND_CAP) cidx[n * CAND_CAP + p] = m4 * 4 + j;
                }
            }
        }
    }
    __syncthreads();
    if (tid == 0) ccnt[n] = cnt < CAND_CAP ? cnt : CAND_CAP;
}

// ---------------------------------------------------------------------------
// K3: per row: exact fp32 logits for candidates, softmax, sparse weighted sum
// ---------------------------------------------------------------------------
__global__ __launch_bounds__(256) void finalize_rows(const float* __restrict__ x,
                                                     const float* __restrict__ dset,
                                                     const int* __restrict__ cidx,
                                                     const int* __restrict__ ccnt,
                                                     float* __restrict__ out) {
    const int n = blockIdx.x;
    const int tid = threadIdx.x;
    const int cnt = ccnt[n];

    __shared__ float L[CAND_CAP];
    __shared__ float wred[4];
    const float4* xr4 = (const float4*)(x + (size_t)n * K_D);

    for (int c = 0; c < cnt; ++c) {
        const float4* dr4 = (const float4*)(dset + (size_t)cidx[n * CAND_CAP + c] * K_D);
        float p = 0.f;
        for (int j = tid; j < K_D / 4; j += 256) {   // 3 iters
            float4 a = xr4[j], b = dr4[j];
            p += a.x * b.x + a.y * b.y + a.z * b.z + a.w * b.w;
        }
#pragma unroll
        for (int off = 32; off > 0; off >>= 1) p += __shfl_down(p, off);
        if ((tid & 63) == 0) wred[tid >> 6] = p;
        __syncthreads();
        if (tid == 0) L[c] = 4.0f * (wred[0] + wred[1] + wred[2] + wred[3]);
        __syncthreads();
    }

    // softmax over candidates (cnt is tiny, thread 0 does it; L becomes weights)
    if (tid == 0) {
        float mx = -3.0e38f;
        for (int c = 0; c < cnt; ++c) mx = fmaxf(mx, L[c]);
        float s = 0.f;
        for (int c = 0; c < cnt; ++c) { float e = expf(L[c] - mx); L[c] = e; s += e; }
        float inv = 1.0f / s;
        for (int c = 0; c < cnt; ++c) L[c] *= inv;
    }
    __syncthreads();

    // out[n][:] = sum_c w_c * dataset[cand_c][:]
    float4* out4 = (float4*)(out + (size_t)n * K_D);
    for (int j = tid; j < K_D / 4; j += 256) {
        float4 o = {0.f, 0.f, 0.f, 0.f};
        for (int c = 0; c < cnt; ++c) {
            float wc = L[c];
            float4 d = *(const float4*)(dset + (size_t)cidx[n * CAND_CAP + c] * K_D + j * 4);
            o.x += wc * d.x; o.y += wc * d.y; o.z += wc * d.z; o.w += wc * d.w;
        }
        out4[j] = o;
    }
}

// ---------------------------------------------------------------------------
extern "C" void kernel_launch(void* const* d_in, const int* in_sizes, int n_in,
                              void* d_out, int out_size, void* d_ws, size_t ws_size,
                              hipStream_t stream) {
    const float* x = (const float*)d_in[0];      // [256,3,32,32]
    const float* dset = (const float*)d_in[1];   // [50000,3,32,32]
    float* out = (float*)d_out;

    // workspace layout (all 256B-aligned):
    //   xb      : 256*3072 bf16      = 1,572,864 B
    //   scores  : 256*50000 fp32     = 51,200,000 B
    //   cidx    : 256*128 int        = 131,072 B
    //   ccnt    : 256 int            = 1,024 B
    char* ws = (char*)d_ws;
    short* xb = (short*)ws;
    float* scores = (float*)(ws + 1572864);
    int* cidx = (int*)(ws + 1572864 + 51200000);
    int* ccnt = (int*)(ws + 1572864 + 51200000 + 131072);

    cvt_x_kernel<<<768, 256, 0, stream>>>(x, xb);
    gemm_scores<<<(M_D + MTILE - 1) / MTILE, 256, 0, stream>>>(xb, dset, scores);
    scan_rows<<<N_Q, 256, 0, stream>>>(scores, cidx, ccnt);
    finalize_rows<<<N_Q, 256, 0, stream>>>(x, dset, cidx, ccnt, out);
}